// Round 5
// baseline (760.269 us; speedup 1.0000x reference)
//
#include <hip/hip_runtime.h>
#include <math.h>

#define BB 2
#define NN 8192
#define KK 16
#define DIMM 64
#define HH 32
#define NBB 5
#define RESS 64
#define NPTS (BB*NN)            // 16384
#define PLANE_ELEMS (BB*3*RESS*RESS*DIMM)   // 1572864
#define PLANE_CELLS (BB*3*RESS*RESS)        // 24576
#define FINF 3.0e38f

// ---------------- zero workspace ----------------
__global__ void zero_kernel(float* __restrict__ p, int n) {
  int t = blockIdx.x * blockDim.x + threadIdx.x;
  if (t < n) p[t] = 0.0f;
}

// ---------------- stem: c = xyz @ w_stem + b_stem ; copy xyz to out ----------------
__global__ void stem_kernel(const float* __restrict__ xyz,
                            const float* __restrict__ w,
                            const float* __restrict__ bias,
                            float* __restrict__ out_xyz,
                            float* __restrict__ c) {
  int tid = blockIdx.x * blockDim.x + threadIdx.x;
  if (tid < NPTS*3) out_xyz[tid] = xyz[tid];
  if (tid < NPTS*DIMM) {
    int p = tid >> 6, d = tid & 63;
    float x = xyz[p*3+0], y = xyz[p*3+1], z = xyz[p*3+2];
    c[tid] = x*w[d] + y*w[64+d] + z*w[128+d] + bias[d];
  }
}

// ---------------- brute-force KNN v4 ----------------
// 512 blocks (2/CU) x 512 threads = 32 queries x 16 candidate slices.
// Same FIFO-push + batched parallel-insert inner loop as v3; finer blocks
// double resident waves/CU for latency hiding. Ties: identical semantics
// (ascending index pushes, strict <, ascending slice merge).
__global__ __launch_bounds__(512) void knn_kernel(const float* __restrict__ xyz,
                                                  int* __restrict__ idx) {
  __shared__ __align__(16) float4 cand[4096];   // 64 KB; partials overlay after scans
  float* part_d = (float*)cand;                 // [256][32] floats (32 KB)
  int*   part_i = (int*)cand + 8192;            // [256][32] ints   (32 KB)

  int t = threadIdx.x;
  int s = t >> 5;                 // slice 0..15
  int ql = t & 31;                // query lane 0..31
  int b = blockIdx.x >> 8;        // batch (256 blocks per batch)
  int q = ((blockIdx.x & 255) << 5) + ql;   // query index in [0,N)
  const float* base = xyz + b*NN*3;

  float qx = base[q*3+0], qy = base[q*3+1], qz = base[q*3+2];
  float qs = qx*qx + qy*qy + qz*qz;

  float bd[16]; int bi[16];
#pragma unroll
  for (int j = 0; j < 16; ++j) { bd[j] = FINF; bi[j] = 0; }

  float fd[4]; int fi[4]; int fcnt = 0;
#pragma unroll
  for (int j = 0; j < 4; ++j) { fd[j] = FINF; fi[j] = 0; }

#define INSERT1(cd, ci)                                                        \
  {                                                                            \
    float _cd = (cd); int _ci = (ci);                                          \
    _Pragma("unroll")                                                          \
    for (int jj = 15; jj >= 1; --jj) {                                         \
      float up = bd[jj-1]; int ui = bi[jj-1];                                  \
      bool shift = _cd < up;                                                   \
      bool here  = _cd < bd[jj];                                               \
      float nv = shift ? up : _cd;                                             \
      int   ni = shift ? ui : _ci;                                             \
      bd[jj] = here ? nv : bd[jj];                                             \
      bi[jj] = here ? ni : bi[jj];                                             \
    }                                                                          \
    bool h0 = _cd < bd[0];                                                     \
    bd[0] = h0 ? _cd : bd[0];                                                  \
    bi[0] = h0 ? _ci : bi[0];                                                  \
  }

#define DRAIN()                                                                \
  {                                                                            \
    _Pragma("unroll")                                                          \
    for (int j2 = 0; j2 < 4; ++j2) {                                           \
      float _dd = (j2 < fcnt) ? fd[j2] : FINF;                                 \
      int   _di = (j2 < fcnt) ? fi[j2] : 0;                                    \
      INSERT1(_dd, _di);                                                       \
    }                                                                          \
    fcnt = 0;                                                                  \
  }

  for (int half = 0; half < 2; ++half) {
    __syncthreads();
    for (int i = t; i < 4096; i += 512) {
      int m = half*4096 + i;
      float xx = base[m*3+0], yy = base[m*3+1], zz = base[m*3+2];
      cand[i] = make_float4(xx, yy, zz, xx*xx + yy*yy + zz*zz);
    }
    __syncthreads();
    int lbase = s*256;            // 16 slices x 256 candidates per half
#pragma unroll 4
    for (int j = 0; j < 256; ++j) {
      float4 c4 = cand[lbase + j];
      float d2 = (qs + c4.w) - 2.0f*(qx*c4.x + qy*c4.y + qz*c4.z);
      if (d2 < bd[15]) {
        int ci = half*4096 + lbase + j;
#pragma unroll
        for (int j2 = 0; j2 < 4; ++j2) {
          fd[j2] = (fcnt == j2) ? d2 : fd[j2];
          fi[j2] = (fcnt == j2) ? ci : fi[j2];
        }
        fcnt++;
      }
      if (__any(fcnt >= 4)) { DRAIN(); }
    }
  }
  DRAIN();
  __syncthreads();
  // write partials: row = s*16 + rank (ascending slice => ascending index range)
#pragma unroll
  for (int j = 0; j < 16; ++j) {
    part_d[(s*16 + j)*32 + ql] = bd[j];
    part_i[(s*16 + j)*32 + ql] = bi[j];
  }
  __syncthreads();
  if (t < 32) {
    float md[16]; int mi[16];
#pragma unroll
    for (int j = 0; j < 16; ++j) { md[j] = FINF; mi[j] = 0; }
    for (int j = 0; j < 256; ++j) {
      float cd = part_d[j*32 + t];
      if (cd < md[15]) {
        int ci = part_i[j*32 + t];
#pragma unroll
        for (int jj = 0; jj < 16; ++jj) {
          if (cd < md[jj]) { float td=md[jj]; int ti=mi[jj]; md[jj]=cd; mi[jj]=ci; cd=td; ci=ti; }
        }
      }
    }
    int* op = idx + (b*NN + q)*16;
#pragma unroll
    for (int j = 0; j < 16; ++j) op[j] = mi[j];
  }
}

// ---------------- x = relu(c @ w0[l] + b0[l]) ----------------
__global__ void xproj_kernel(const float* __restrict__ c,
                             const float* __restrict__ w0,
                             const float* __restrict__ b0,
                             float* __restrict__ x, int layer) {
  int tid = blockIdx.x * blockDim.x + threadIdx.x;
  if (tid >= NPTS*HH) return;
  int p = tid >> 5, h = tid & 31;
  const float* w = w0 + layer*DIMM*HH;
  const float* cr = c + p*DIMM;
  float acc = b0[layer*HH + h];
#pragma unroll
  for (int d = 0; d < DIMM; ++d) acc += cr[d]*w[d*HH + h];
  x[tid] = fmaxf(acc, 0.0f);
}

// ---------------- fused FKAConv v3: 256 thr = 4 waves = 4 points ----------------
// Scratch squeezed: FB overlays M1+M2 (dead after stage C; barrier-separated)
// -> 39104 B/block -> 4 blocks/CU.
#define OFF_W1   0
#define OFF_W2AT 48        // [16][20] transposed fc2 rows 0..15
#define OFF_W2BT 368       // [16][20] transposed fc2 rows 16..31
#define OFF_W3AT 688
#define OFF_W3BT 1008
#define OFF_WL   1328      // w2 final proj [32][64]
#define OFF_B2   3376      // [64]
#define OFF_RED  3440      // y partials [8 seg][4 pt][32 o]
#define OFF_Y    4464      // [4 pt][32 o]
#define OFF_SCR  4592      // per-wave scratch x4
#define SCR_SZ   1296
#define S_DW 0             // [16]
#define S_M1 16            // [16][16]
#define S_M2 272           // [16][16]
#define S_MM 528           // [16][16]
#define S_XN 784           // [16][32]
#define S_FB 16            // f [32 c][16 s] — overlays M1+M2
#define LDS_TOT (OFF_SCR + 4*SCR_SZ)   // 9776 floats = 39104 B

__global__ __launch_bounds__(256) void conv_kernel(
    float* __restrict__ c, const float* __restrict__ x,
    const int* __restrict__ idx, const float* __restrict__ xyz,
    const float* __restrict__ fc1, const float* __restrict__ fc2,
    const float* __restrict__ fc3, const float* __restrict__ wcv,
    const float* __restrict__ alpha, const float* __restrict__ beta,
    const float* __restrict__ w2, const float* __restrict__ b2, int layer)
{
  __shared__ __align__(16) float lds[LDS_TOT];
  int t = threadIdx.x;

  const float* fc1l = fc1 + layer*3*KK;
  const float* fc2l = fc2 + layer*2*KK*KK;
  const float* fc3l = fc3 + layer*2*KK*KK;
  const float* wcvl = wcv + layer*HH*HH*KK;
  const float* w2l  = w2  + layer*HH*DIMM;
  const float* b2l  = b2  + layer*DIMM;

  // ---- stage weights once per block ----
  if (t < 48) lds[OFF_W1 + t] = fc1l[t];
  {
    int s = t >> 4, tt = t & 15;
    lds[OFF_W2AT + s*20 + tt] = fc2l[tt*16 + s];
    lds[OFF_W2BT + s*20 + tt] = fc2l[(16+tt)*16 + s];
    lds[OFF_W3AT + s*20 + tt] = fc3l[tt*16 + s];
    lds[OFF_W3BT + s*20 + tt] = fc3l[(16+tt)*16 + s];
  }
#pragma unroll
  for (int r = 0; r < 8; ++r) lds[OFF_WL + t + 256*r] = w2l[t + 256*r];
  if (t < 64) lds[OFF_B2 + t] = b2l[t];
  __syncthreads();

  int wv = t >> 6, lane = t & 63;
  int p = blockIdx.x*4 + wv;          // global point
  int b = p >> 13;
  float* scr = lds + OFF_SCR + wv*SCR_SZ;
  int sI = lane & 15;

  // ---- group A: dw, xn gather, m1 ----
  float qxx = xyz[p*3+0], qyy = xyz[p*3+1], qzz = xyz[p*3+2];
  float alv = alpha[layer], bev = beta[layer];
  int jidx = 0; float px = 0, py = 0, pz = 0, sv = 0;
  if (lane < 16) {
    jidx = idx[p*16 + lane];
    const float* nb = xyz + ((long)b*NN + jidx)*3;
    px = nb[0]-qxx; py = nb[1]-qyy; pz = nb[2]-qzz;
    float dd = sqrtf(px*px + py*py + pz*pz + 1e-12f);
    sv = 1.0f/(1.0f + expf(alv*dd - bev));     // sigmoid(-a*d+b)
  }
  float ssum = 0.0f;                            // serial ascending-k sum (matches ref order)
#pragma unroll
  for (int k = 0; k < 16; ++k) ssum += __shfl(sv, k);
  if (lane < 16) scr[S_DW + lane] = sv / (ssum + 1e-6f) * 16.0f;
  // xn gather: 128 float4 tasks over 64 lanes x2
#pragma unroll
  for (int r = 0; r < 2; ++r) {
    int tsk = lane + 64*r;
    int k = tsk >> 3, seg = tsk & 7;
    int jk = __shfl(jidx, k);
    float4 v = *(const float4*)(x + ((long)b*NN + jk)*32 + seg*4);
    *(float4*)&scr[S_XN + k*32 + seg*4] = v;
  }
  // m1 = relu(pts @ fc1): pts via shuffle from lanes 0..15
#pragma unroll
  for (int r = 0; r < 4; ++r) {
    int k = (lane >> 4) + 4*r;
    float pxk = __shfl(px, k), pyk = __shfl(py, k), pzk = __shfl(pz, k);
    float v = pxk*lds[OFF_W1+sI] + pyk*lds[OFF_W1+16+sI] + pzk*lds[OFF_W1+32+sI];
    scr[S_M1 + k*16 + sI] = fmaxf(v, 0.0f);
  }
  __syncthreads();

  // ---- group B: mp1, q1 (shuffle), m2 ----
  {
    float mpv = 0.0f;
#pragma unroll
    for (int k = 0; k < 16; ++k) mpv = fmaxf(mpv, scr[S_M1 + k*16 + sI] * scr[S_DW + k]);
    float qv = 0.0f;
#pragma unroll
    for (int tt = 0; tt < 16; ++tt) qv += __shfl(mpv, tt) * lds[OFF_W2BT + sI*20 + tt];
    float4 wa0 = *(float4*)&lds[OFF_W2AT + sI*20 + 0];
    float4 wa1 = *(float4*)&lds[OFF_W2AT + sI*20 + 4];
    float4 wa2 = *(float4*)&lds[OFF_W2AT + sI*20 + 8];
    float4 wa3 = *(float4*)&lds[OFF_W2AT + sI*20 + 12];
#pragma unroll
    for (int r = 0; r < 4; ++r) {
      int k = (lane >> 4) + 4*r;
      float4 m0 = *(float4*)&scr[S_M1 + k*16 + 0];
      float4 m1_ = *(float4*)&scr[S_M1 + k*16 + 4];
      float4 m2_ = *(float4*)&scr[S_M1 + k*16 + 8];
      float4 m3_ = *(float4*)&scr[S_M1 + k*16 + 12];
      float v = qv;
      v += m0.x*wa0.x; v += m0.y*wa0.y; v += m0.z*wa0.z; v += m0.w*wa0.w;
      v += m1_.x*wa1.x; v += m1_.y*wa1.y; v += m1_.z*wa1.z; v += m1_.w*wa1.w;
      v += m2_.x*wa2.x; v += m2_.y*wa2.y; v += m2_.z*wa2.z; v += m2_.w*wa2.w;
      v += m3_.x*wa3.x; v += m3_.y*wa3.y; v += m3_.z*wa3.z; v += m3_.w*wa3.w;
      scr[S_M2 + k*16 + sI] = fmaxf(v, 0.0f);
    }
  }
  __syncthreads();

  // ---- group C: mp2, q2, m3 -> mm = relu(.)*dw ----
  {
    float mpv = 0.0f;
#pragma unroll
    for (int k = 0; k < 16; ++k) mpv = fmaxf(mpv, scr[S_M2 + k*16 + sI] * scr[S_DW + k]);
    float qv = 0.0f;
#pragma unroll
    for (int tt = 0; tt < 16; ++tt) qv += __shfl(mpv, tt) * lds[OFF_W3BT + sI*20 + tt];
    float4 wa0 = *(float4*)&lds[OFF_W3AT + sI*20 + 0];
    float4 wa1 = *(float4*)&lds[OFF_W3AT + sI*20 + 4];
    float4 wa2 = *(float4*)&lds[OFF_W3AT + sI*20 + 8];
    float4 wa3 = *(float4*)&lds[OFF_W3AT + sI*20 + 12];
#pragma unroll
    for (int r = 0; r < 4; ++r) {
      int k = (lane >> 4) + 4*r;
      float4 m0 = *(float4*)&scr[S_M2 + k*16 + 0];
      float4 m1_ = *(float4*)&scr[S_M2 + k*16 + 4];
      float4 m2_ = *(float4*)&scr[S_M2 + k*16 + 8];
      float4 m3_ = *(float4*)&scr[S_M2 + k*16 + 12];
      float v = qv;
      v += m0.x*wa0.x; v += m0.y*wa0.y; v += m0.z*wa0.z; v += m0.w*wa0.w;
      v += m1_.x*wa1.x; v += m1_.y*wa1.y; v += m1_.z*wa1.z; v += m1_.w*wa1.w;
      v += m2_.x*wa2.x; v += m2_.y*wa2.y; v += m2_.z*wa2.z; v += m2_.w*wa2.w;
      v += m3_.x*wa3.x; v += m3_.y*wa3.y; v += m3_.z*wa3.z; v += m3_.w*wa3.w;
      scr[S_MM + k*16 + sI] = fmaxf(v, 0.0f) * scr[S_DW + k];
    }
  }
  __syncthreads();

  // ---- group D: f[c][s] = sum_k xn[k][c]*mm[k][s], 8 c-values per lane in regs ----
  // writes FB over dead M1+M2
  {
    int q4 = lane >> 4;
    float fr0=0,fr1=0,fr2=0,fr3=0,fr4=0,fr5=0,fr6=0,fr7=0;
#pragma unroll
    for (int k = 0; k < 16; ++k) {
      float mmv = scr[S_MM + k*16 + sI];
      float4 a  = *(float4*)&scr[S_XN + k*32 + q4*8];
      float4 bb = *(float4*)&scr[S_XN + k*32 + q4*8 + 4];
      fr0 += a.x*mmv;  fr1 += a.y*mmv;  fr2 += a.z*mmv;  fr3 += a.w*mmv;
      fr4 += bb.x*mmv; fr5 += bb.y*mmv; fr6 += bb.z*mmv; fr7 += bb.w*mmv;
    }
    scr[S_FB + (q4*8+0)*16 + sI] = fr0;
    scr[S_FB + (q4*8+1)*16 + sI] = fr1;
    scr[S_FB + (q4*8+2)*16 + sI] = fr2;
    scr[S_FB + (q4*8+3)*16 + sI] = fr3;
    scr[S_FB + (q4*8+4)*16 + sI] = fr4;
    scr[S_FB + (q4*8+5)*16 + sI] = fr5;
    scr[S_FB + (q4*8+6)*16 + sI] = fr6;
    scr[S_FB + (q4*8+7)*16 + sI] = fr7;
  }
  __syncthreads();

  // ---- block GEMM y-einsum: thread (o, seg): wcv read ONCE per block ----
  {
    int o = t & 31, seg = t >> 5;          // 8 segs x 64 cs
    const float4* wrow = (const float4*)(wcvl + o*512 + seg*64);
    float acc0=0, acc1=0, acc2=0, acc3=0;
#pragma unroll
    for (int j = 0; j < 16; ++j) {
      float4 w4 = wrow[j];
      float4 f0 = *(const float4*)&lds[OFF_SCR + 0*SCR_SZ + S_FB + seg*64 + j*4];
      float4 f1 = *(const float4*)&lds[OFF_SCR + 1*SCR_SZ + S_FB + seg*64 + j*4];
      float4 f2 = *(const float4*)&lds[OFF_SCR + 2*SCR_SZ + S_FB + seg*64 + j*4];
      float4 f3 = *(const float4*)&lds[OFF_SCR + 3*SCR_SZ + S_FB + seg*64 + j*4];
      acc0 += w4.x*f0.x; acc0 += w4.y*f0.y; acc0 += w4.z*f0.z; acc0 += w4.w*f0.w;
      acc1 += w4.x*f1.x; acc1 += w4.y*f1.y; acc1 += w4.z*f1.z; acc1 += w4.w*f1.w;
      acc2 += w4.x*f2.x; acc2 += w4.y*f2.y; acc2 += w4.z*f2.z; acc2 += w4.w*f2.w;
      acc3 += w4.x*f3.x; acc3 += w4.y*f3.y; acc3 += w4.z*f3.z; acc3 += w4.w*f3.w;
    }
    lds[OFF_RED + seg*128 + 0*32 + o] = acc0;
    lds[OFF_RED + seg*128 + 1*32 + o] = acc1;
    lds[OFF_RED + seg*128 + 2*32 + o] = acc2;
    lds[OFF_RED + seg*128 + 3*32 + o] = acc3;
  }
  __syncthreads();

  // ---- reduce segs + relu ----
  if (t < 128) {
    int pt = t >> 5, o = t & 31;
    float yv = 0.0f;
#pragma unroll
    for (int seg = 0; seg < 8; ++seg) yv += lds[OFF_RED + seg*128 + pt*32 + o];
    lds[OFF_Y + pt*32 + o] = fmaxf(yv, 0.0f);
  }
  __syncthreads();

  // ---- final: c = relu(y @ w2 + b2 + c), 1 output/thread ----
  {
    int pt = t >> 6, d = t & 63;
    float zv = lds[OFF_B2 + d];
#pragma unroll
    for (int o = 0; o < 32; ++o) zv += lds[OFF_Y + pt*32 + o] * lds[OFF_WL + o*64 + d];
    int gp = blockIdx.x*4 + pt;
    float cv = c[gp*64 + d];
    c[gp*64 + d] = fmaxf(zv + cv, 0.0f);
  }
}

// ---------------- triplane scatter-accumulate ----------------
__global__ void triacc_kernel(const float* __restrict__ c,
                              const float* __restrict__ xyz,
                              float* __restrict__ psum,
                              float* __restrict__ pcnt) {
  int tid = blockIdx.x * blockDim.x + threadIdx.x;
  if (tid >= NPTS*DIMM) return;
  int p = tid >> 6, d = tid & 63;
  int b = p >> 13;
  float p0 = xyz[p*3+0] / 1.101f + 0.5f;
  float p1 = xyz[p*3+1] / 1.101f + 0.5f;
  float p2 = xyz[p*3+2] / 1.101f + 0.5f;
  int i0 = min(max((int)(p0*64.0f), 0), 63);
  int i1 = min(max((int)(p1*64.0f), 0), 63);
  int i2 = min(max((int)(p2*64.0f), 0), 63);
  int cb = b*3*RESS*RESS;
  int c0 = cb + 0*RESS*RESS + i0*RESS + i1;   // xy plane
  int c1 = cb + 1*RESS*RESS + i0*RESS + i2;   // xz plane
  int c2 = cb + 2*RESS*RESS + i1*RESS + i2;   // yz plane
  float v = c[tid];
  atomicAdd(&psum[c0*DIMM + d], v);
  atomicAdd(&psum[c1*DIMM + d], v);
  atomicAdd(&psum[c2*DIMM + d], v);
  if (d == 0) {
    atomicAdd(&pcnt[c0], 1.0f);
    atomicAdd(&pcnt[c1], 1.0f);
    atomicAdd(&pcnt[c2], 1.0f);
  }
}

// ---------------- triplane normalize ----------------
__global__ void trinorm_kernel(const float* __restrict__ psum,
                               const float* __restrict__ pcnt,
                               float* __restrict__ out) {
  int tid = blockIdx.x * blockDim.x + threadIdx.x;
  if (tid >= PLANE_ELEMS) return;
  float cnt = pcnt[tid >> 6];
  out[tid] = psum[tid] / fmaxf(cnt, 1.0f);
}

extern "C" void kernel_launch(void* const* d_in, const int* in_sizes, int n_in,
                              void* d_out, int out_size, void* d_ws, size_t ws_size,
                              hipStream_t stream) {
  const float* xyz   = (const float*)d_in[0];
  const float* wstem = (const float*)d_in[1];
  const float* bstem = (const float*)d_in[2];
  const float* w0    = (const float*)d_in[3];
  const float* b0    = (const float*)d_in[4];
  const float* fc1   = (const float*)d_in[5];
  const float* fc2   = (const float*)d_in[6];
  const float* fc3   = (const float*)d_in[7];
  const float* wcv   = (const float*)d_in[8];
  const float* alpha = (const float*)d_in[9];
  const float* beta  = (const float*)d_in[10];
  const float* w2    = (const float*)d_in[11];
  const float* b2    = (const float*)d_in[12];

  float* out     = (float*)d_out;
  float* out_xyz = out;                       // 49152
  float* c       = out + NPTS*3;              // working c buffer
  float* out_tri = c + NPTS*DIMM;             // 1572864

  float* wsf  = (float*)d_ws;
  int*   idx  = (int*)d_ws;                   // NPTS*16 int32
  float* x    = wsf + NPTS*16;                // NPTS*32
  float* psum = x + NPTS*HH;                  // PLANE_ELEMS
  float* pcnt = psum + PLANE_ELEMS;           // PLANE_CELLS

  int nz = PLANE_ELEMS + PLANE_CELLS;
  zero_kernel<<<(nz+255)/256, 256, 0, stream>>>(psum, nz);
  stem_kernel<<<(NPTS*DIMM+255)/256, 256, 0, stream>>>(xyz, wstem, bstem, out_xyz, c);
  knn_kernel<<<512, 512, 0, stream>>>(xyz, idx);
  for (int layer = 0; layer < NBB; ++layer) {
    xproj_kernel<<<(NPTS*HH+255)/256, 256, 0, stream>>>(c, w0, b0, x, layer);
    conv_kernel<<<NPTS/4, 256, 0, stream>>>(c, x, idx, xyz, fc1, fc2, fc3, wcv,
                                            alpha, beta, w2, b2, layer);
  }
  triacc_kernel<<<(NPTS*DIMM+255)/256, 256, 0, stream>>>(c, xyz, psum, pcnt);
  trinorm_kernel<<<(PLANE_ELEMS+255)/256, 256, 0, stream>>>(psum, pcnt, out_tri);
}

// Round 6
// 591.228 us; speedup vs baseline: 1.2859x; 1.2859x over previous
//
#include <hip/hip_runtime.h>
#include <math.h>

#define BB 2
#define NN 8192
#define KK 16
#define DIMM 64
#define HH 32
#define NBB 5
#define RESS 64
#define NPTS (BB*NN)            // 16384
#define PLANE_ELEMS (BB*3*RESS*RESS*DIMM)   // 1572864
#define PLANE_CELLS (BB*3*RESS*RESS)        // 24576
#define GC 8                    // knn grid cells per dim
#define GCS 0.125f              // cell size
#define NCELL (GC*GC*GC)        // 512 per batch

// ---------------- zero workspace ----------------
__global__ void zero_kernel(float* __restrict__ p, int n) {
  int t = blockIdx.x * blockDim.x + threadIdx.x;
  if (t < n) p[t] = 0.0f;
}

// ---------------- stem: c = xyz @ w_stem + b_stem ; copy xyz to out ----------------
__global__ void stem_kernel(const float* __restrict__ xyz,
                            const float* __restrict__ w,
                            const float* __restrict__ bias,
                            float* __restrict__ out_xyz,
                            float* __restrict__ c) {
  int tid = blockIdx.x * blockDim.x + threadIdx.x;
  if (tid < NPTS*3) out_xyz[tid] = xyz[tid];
  if (tid < NPTS*DIMM) {
    int p = tid >> 6, d = tid & 63;
    float x = xyz[p*3+0], y = xyz[p*3+1], z = xyz[p*3+2];
    c[tid] = x*w[d] + y*w[64+d] + z*w[128+d] + bias[d];
  }
}

// ---------------- binned exact KNN ----------------
__device__ __forceinline__ unsigned ord32(float f) {
  unsigned u = __float_as_uint(f);
  return u ^ ((unsigned)((int)u >> 31) | 0x80000000u);
}
__device__ __forceinline__ int cell_of(float v) {
  return min(max((int)((v + 0.5f) * 8.0f), 0), 7);
}

__global__ void knn_count_kernel(const float* __restrict__ xyz,
                                 int* __restrict__ cellcnt) {
  int p = blockIdx.x * blockDim.x + threadIdx.x;
  if (p >= NPTS) return;
  int bq = p >> 13;
  float px = xyz[p*3], py = xyz[p*3+1], pz = xyz[p*3+2];
  int cc = (cell_of(px) << 6) | (cell_of(py) << 3) | cell_of(pz);
  atomicAdd(&cellcnt[(bq << 9) | cc], 1);
}

__global__ __launch_bounds__(1024) void knn_scan_kernel(const int* __restrict__ cnt,
                                                        int* __restrict__ cellstart,
                                                        int* __restrict__ cellcur) {
  __shared__ int s[1024];
  int t = threadIdx.x;
  int v = cnt[t];
  s[t] = v;
  __syncthreads();
  for (int off = 1; off < 1024; off <<= 1) {
    int add = (t >= off) ? s[t-off] : 0;
    __syncthreads();
    s[t] += add;
    __syncthreads();
  }
  int inc = s[t];
  cellstart[t+1] = inc;
  if (t == 0) cellstart[0] = 0;
  cellcur[t] = inc - v;      // exclusive start, used as scatter cursor
}

__global__ void knn_scatter_kernel(const float* __restrict__ xyz,
                                   int* __restrict__ cellcur,
                                   float4* __restrict__ spts) {
  int p = blockIdx.x * blockDim.x + threadIdx.x;
  if (p >= NPTS) return;
  int bq = p >> 13;
  float px = xyz[p*3], py = xyz[p*3+1], pz = xyz[p*3+2];
  int cc = (cell_of(px) << 6) | (cell_of(py) << 3) | cell_of(pz);
  int pos = atomicAdd(&cellcur[(bq << 9) | cc], 1);
  spts[pos] = make_float4(px, py, pz, __int_as_float(p & (NN-1)));
}

// One wave per cell (1024 waves). Exact: ring expansion with guarantee
// bd15_d2 < (r*cs - 1e-4)^2 => no unscanned point can enter top-16
// (margin covers fp d2 error ~3e-7 and binning-boundary ulp displacement).
// Selection key = (orderable(d2) << 32) | neighbor_idx: exact stable top-k,
// order-independent; d2 formula identical to the validated brute force.
#define INS64(key)                                                             \
  {                                                                            \
    unsigned long long _k = (key);                                             \
    _Pragma("unroll")                                                          \
    for (int jj = 15; jj >= 1; --jj) {                                         \
      unsigned long long up = bd[jj-1];                                        \
      bool shift = _k < up;                                                    \
      bool here  = _k < bd[jj];                                                \
      unsigned long long nv = shift ? up : _k;                                 \
      bd[jj] = here ? nv : bd[jj];                                             \
    }                                                                          \
    bd[0] = (_k < bd[0]) ? _k : bd[0];                                         \
  }
#define DRAIN64()                                                              \
  {                                                                            \
    INS64((0 < fcnt) ? fd[0] : ~0ull);                                         \
    INS64((1 < fcnt) ? fd[1] : ~0ull);                                         \
    INS64((2 < fcnt) ? fd[2] : ~0ull);                                         \
    INS64((3 < fcnt) ? fd[3] : ~0ull);                                         \
    fcnt = 0; hi15 = (unsigned)(bd[15] >> 32);                                 \
  }

__global__ __launch_bounds__(64) void knn_query_kernel(
    const float4* __restrict__ spts, const int* __restrict__ cellstart,
    int* __restrict__ idx) {
  int wave = blockIdx.x;            // 0..1023
  int b = wave >> 9;
  int cell = wave & 511;            // (cx<<6)|(cy<<3)|cz
  int cx = cell >> 6, cy = (cell >> 3) & 7, cz = cell & 7;
  int cb = b << 9;
  int qlo = cellstart[cb + cell], qhi = cellstart[cb + cell + 1];
  int nq = qhi - qlo;
  if (nq <= 0) return;
  int lane = threadIdx.x;
  for (int qb = 0; qb < nq; qb += 64) {
    bool valid = (qb + lane) < nq;
    int qpos = qlo + (valid ? qb + lane : 0);
    float4 qv = spts[qpos];
    float qx = qv.x, qy = qv.y, qz = qv.z;
    float qs = qx*qx + qy*qy + qz*qz;
    unsigned long long bd[16];
#pragma unroll
    for (int j = 0; j < 16; ++j) bd[j] = ~0ull;
    unsigned long long fd[4] = {0,0,0,0};
    int fcnt = 0;
    unsigned hi15 = 0xFFFFFFFFu;
    bool done = !valid;
    for (int r = 1; r <= 8; ++r) {
      int x0 = max(cx-r,0), x1 = min(cx+r,7);
      int y0 = max(cy-r,0), y1 = min(cy+r,7);
      int z0 = max(cz-r,0), z1 = min(cz+r,7);
      for (int xx = x0; xx <= x1; ++xx)
      for (int yy = y0; yy <= y1; ++yy)
      for (int zz = z0; zz <= z1; ++zz) {
        if (r > 1) {   // skip cells already scanned in box r-1
          int pr = r - 1;
          if (xx >= cx-pr && xx <= cx+pr && yy >= cy-pr && yy <= cy+pr &&
              zz >= cz-pr && zz <= cz+pr) continue;
        }
        int c2 = cb + (xx << 6) + (yy << 3) + zz;
        int jlo = cellstart[c2], jhi = cellstart[c2+1];
        for (int j = jlo; j < jhi; ++j) {
          float4 c4 = spts[j];                       // wave-uniform broadcast
          float sq = c4.x*c4.x + c4.y*c4.y + c4.z*c4.z;
          float d2 = (qs + sq) - 2.0f*(qx*c4.x + qy*c4.y + qz*c4.z);
          unsigned du = ord32(d2);
          if (valid && du <= hi15) {                 // conservative; dup-free
            unsigned long long key =
                ((unsigned long long)du << 32) | (unsigned)__float_as_int(c4.w);
            fd[0] = (fcnt==0)?key:fd[0];
            fd[1] = (fcnt==1)?key:fd[1];
            fd[2] = (fcnt==2)?key:fd[2];
            fd[3] = (fcnt==3)?key:fd[3];
            fcnt++;
          }
          if (__any(fcnt >= 4)) { DRAIN64(); }
        }
      }
      if (__any(fcnt > 0)) { DRAIN64(); }
      float thr = (float)r * GCS - 1e-4f;
      unsigned thru = ord32(thr * thr);
      done = done || ((unsigned)(bd[15] >> 32) < thru);
      if (!__any(!done)) break;
    }
    if (valid) {
      int n_self = __float_as_int(qv.w);
      int* op = idx + (((long)b << 13) + n_self) * 16;
#pragma unroll
      for (int j = 0; j < 16; ++j) op[j] = (int)(unsigned)(bd[j] & 0xffffffffu);
    }
  }
}

// ---------------- x = relu(c @ w0[l] + b0[l]) ----------------
__global__ void xproj_kernel(const float* __restrict__ c,
                             const float* __restrict__ w0,
                             const float* __restrict__ b0,
                             float* __restrict__ x, int layer) {
  int tid = blockIdx.x * blockDim.x + threadIdx.x;
  if (tid >= NPTS*HH) return;
  int p = tid >> 5, h = tid & 31;
  const float* w = w0 + layer*DIMM*HH;
  const float* cr = c + p*DIMM;
  float acc = b0[layer*HH + h];
#pragma unroll
  for (int d = 0; d < DIMM; ++d) acc += cr[d]*w[d*HH + h];
  x[tid] = fmaxf(acc, 0.0f);
}

// ---------------- fused FKAConv v3: 256 thr = 4 waves = 4 points ----------------
#define OFF_W1   0
#define OFF_W2AT 48
#define OFF_W2BT 368
#define OFF_W3AT 688
#define OFF_W3BT 1008
#define OFF_WL   1328
#define OFF_B2   3376
#define OFF_RED  3440
#define OFF_Y    4464
#define OFF_SCR  4592
#define SCR_SZ   1296
#define S_DW 0
#define S_M1 16
#define S_M2 272
#define S_MM 528
#define S_XN 784
#define S_FB 16            // overlays M1+M2 (dead after stage C)
#define LDS_TOT (OFF_SCR + 4*SCR_SZ)   // 9776 floats = 39104 B -> 4 blocks/CU

__global__ __launch_bounds__(256) void conv_kernel(
    float* __restrict__ c, const float* __restrict__ x,
    const int* __restrict__ idx, const float* __restrict__ xyz,
    const float* __restrict__ fc1, const float* __restrict__ fc2,
    const float* __restrict__ fc3, const float* __restrict__ wcv,
    const float* __restrict__ alpha, const float* __restrict__ beta,
    const float* __restrict__ w2, const float* __restrict__ b2, int layer)
{
  __shared__ __align__(16) float lds[LDS_TOT];
  int t = threadIdx.x;

  const float* fc1l = fc1 + layer*3*KK;
  const float* fc2l = fc2 + layer*2*KK*KK;
  const float* fc3l = fc3 + layer*2*KK*KK;
  const float* wcvl = wcv + layer*HH*HH*KK;
  const float* w2l  = w2  + layer*HH*DIMM;
  const float* b2l  = b2  + layer*DIMM;

  if (t < 48) lds[OFF_W1 + t] = fc1l[t];
  {
    int s = t >> 4, tt = t & 15;
    lds[OFF_W2AT + s*20 + tt] = fc2l[tt*16 + s];
    lds[OFF_W2BT + s*20 + tt] = fc2l[(16+tt)*16 + s];
    lds[OFF_W3AT + s*20 + tt] = fc3l[tt*16 + s];
    lds[OFF_W3BT + s*20 + tt] = fc3l[(16+tt)*16 + s];
  }
#pragma unroll
  for (int r = 0; r < 8; ++r) lds[OFF_WL + t + 256*r] = w2l[t + 256*r];
  if (t < 64) lds[OFF_B2 + t] = b2l[t];
  __syncthreads();

  int wv = t >> 6, lane = t & 63;
  int p = blockIdx.x*4 + wv;
  int b = p >> 13;
  float* scr = lds + OFF_SCR + wv*SCR_SZ;
  int sI = lane & 15;

  float qxx = xyz[p*3+0], qyy = xyz[p*3+1], qzz = xyz[p*3+2];
  float alv = alpha[layer], bev = beta[layer];
  int jidx = 0; float px = 0, py = 0, pz = 0, sv = 0;
  if (lane < 16) {
    jidx = idx[p*16 + lane];
    const float* nb = xyz + ((long)b*NN + jidx)*3;
    px = nb[0]-qxx; py = nb[1]-qyy; pz = nb[2]-qzz;
    float dd = sqrtf(px*px + py*py + pz*pz + 1e-12f);
    sv = 1.0f/(1.0f + expf(alv*dd - bev));
  }
  float ssum = 0.0f;
#pragma unroll
  for (int k = 0; k < 16; ++k) ssum += __shfl(sv, k);
  if (lane < 16) scr[S_DW + lane] = sv / (ssum + 1e-6f) * 16.0f;
#pragma unroll
  for (int r = 0; r < 2; ++r) {
    int tsk = lane + 64*r;
    int k = tsk >> 3, seg = tsk & 7;
    int jk = __shfl(jidx, k);
    float4 v = *(const float4*)(x + ((long)b*NN + jk)*32 + seg*4);
    *(float4*)&scr[S_XN + k*32 + seg*4] = v;
  }
#pragma unroll
  for (int r = 0; r < 4; ++r) {
    int k = (lane >> 4) + 4*r;
    float pxk = __shfl(px, k), pyk = __shfl(py, k), pzk = __shfl(pz, k);
    float v = pxk*lds[OFF_W1+sI] + pyk*lds[OFF_W1+16+sI] + pzk*lds[OFF_W1+32+sI];
    scr[S_M1 + k*16 + sI] = fmaxf(v, 0.0f);
  }
  __syncthreads();

  {
    float mpv = 0.0f;
#pragma unroll
    for (int k = 0; k < 16; ++k) mpv = fmaxf(mpv, scr[S_M1 + k*16 + sI] * scr[S_DW + k]);
    float qv = 0.0f;
#pragma unroll
    for (int tt = 0; tt < 16; ++tt) qv += __shfl(mpv, tt) * lds[OFF_W2BT + sI*20 + tt];
    float4 wa0 = *(float4*)&lds[OFF_W2AT + sI*20 + 0];
    float4 wa1 = *(float4*)&lds[OFF_W2AT + sI*20 + 4];
    float4 wa2 = *(float4*)&lds[OFF_W2AT + sI*20 + 8];
    float4 wa3 = *(float4*)&lds[OFF_W2AT + sI*20 + 12];
#pragma unroll
    for (int r = 0; r < 4; ++r) {
      int k = (lane >> 4) + 4*r;
      float4 m0 = *(float4*)&scr[S_M1 + k*16 + 0];
      float4 m1_ = *(float4*)&scr[S_M1 + k*16 + 4];
      float4 m2_ = *(float4*)&scr[S_M1 + k*16 + 8];
      float4 m3_ = *(float4*)&scr[S_M1 + k*16 + 12];
      float v = qv;
      v += m0.x*wa0.x; v += m0.y*wa0.y; v += m0.z*wa0.z; v += m0.w*wa0.w;
      v += m1_.x*wa1.x; v += m1_.y*wa1.y; v += m1_.z*wa1.z; v += m1_.w*wa1.w;
      v += m2_.x*wa2.x; v += m2_.y*wa2.y; v += m2_.z*wa2.z; v += m2_.w*wa2.w;
      v += m3_.x*wa3.x; v += m3_.y*wa3.y; v += m3_.z*wa3.z; v += m3_.w*wa3.w;
      scr[S_M2 + k*16 + sI] = fmaxf(v, 0.0f);
    }
  }
  __syncthreads();

  {
    float mpv = 0.0f;
#pragma unroll
    for (int k = 0; k < 16; ++k) mpv = fmaxf(mpv, scr[S_M2 + k*16 + sI] * scr[S_DW + k]);
    float qv = 0.0f;
#pragma unroll
    for (int tt = 0; tt < 16; ++tt) qv += __shfl(mpv, tt) * lds[OFF_W3BT + sI*20 + tt];
    float4 wa0 = *(float4*)&lds[OFF_W3AT + sI*20 + 0];
    float4 wa1 = *(float4*)&lds[OFF_W3AT + sI*20 + 4];
    float4 wa2 = *(float4*)&lds[OFF_W3AT + sI*20 + 8];
    float4 wa3 = *(float4*)&lds[OFF_W3AT + sI*20 + 12];
#pragma unroll
    for (int r = 0; r < 4; ++r) {
      int k = (lane >> 4) + 4*r;
      float4 m0 = *(float4*)&scr[S_M2 + k*16 + 0];
      float4 m1_ = *(float4*)&scr[S_M2 + k*16 + 4];
      float4 m2_ = *(float4*)&scr[S_M2 + k*16 + 8];
      float4 m3_ = *(float4*)&scr[S_M2 + k*16 + 12];
      float v = qv;
      v += m0.x*wa0.x; v += m0.y*wa0.y; v += m0.z*wa0.z; v += m0.w*wa0.w;
      v += m1_.x*wa1.x; v += m1_.y*wa1.y; v += m1_.z*wa1.z; v += m1_.w*wa1.w;
      v += m2_.x*wa2.x; v += m2_.y*wa2.y; v += m2_.z*wa2.z; v += m2_.w*wa2.w;
      v += m3_.x*wa3.x; v += m3_.y*wa3.y; v += m3_.z*wa3.z; v += m3_.w*wa3.w;
      scr[S_MM + k*16 + sI] = fmaxf(v, 0.0f) * scr[S_DW + k];
    }
  }
  __syncthreads();

  {
    int q4 = lane >> 4;
    float fr0=0,fr1=0,fr2=0,fr3=0,fr4=0,fr5=0,fr6=0,fr7=0;
#pragma unroll
    for (int k = 0; k < 16; ++k) {
      float mmv = scr[S_MM + k*16 + sI];
      float4 a  = *(float4*)&scr[S_XN + k*32 + q4*8];
      float4 bb = *(float4*)&scr[S_XN + k*32 + q4*8 + 4];
      fr0 += a.x*mmv;  fr1 += a.y*mmv;  fr2 += a.z*mmv;  fr3 += a.w*mmv;
      fr4 += bb.x*mmv; fr5 += bb.y*mmv; fr6 += bb.z*mmv; fr7 += bb.w*mmv;
    }
    scr[S_FB + (q4*8+0)*16 + sI] = fr0;
    scr[S_FB + (q4*8+1)*16 + sI] = fr1;
    scr[S_FB + (q4*8+2)*16 + sI] = fr2;
    scr[S_FB + (q4*8+3)*16 + sI] = fr3;
    scr[S_FB + (q4*8+4)*16 + sI] = fr4;
    scr[S_FB + (q4*8+5)*16 + sI] = fr5;
    scr[S_FB + (q4*8+6)*16 + sI] = fr6;
    scr[S_FB + (q4*8+7)*16 + sI] = fr7;
  }
  __syncthreads();

  {
    int o = t & 31, seg = t >> 5;
    const float4* wrow = (const float4*)(wcvl + o*512 + seg*64);
    float acc0=0, acc1=0, acc2=0, acc3=0;
#pragma unroll
    for (int j = 0; j < 16; ++j) {
      float4 w4 = wrow[j];
      float4 f0 = *(const float4*)&lds[OFF_SCR + 0*SCR_SZ + S_FB + seg*64 + j*4];
      float4 f1 = *(const float4*)&lds[OFF_SCR + 1*SCR_SZ + S_FB + seg*64 + j*4];
      float4 f2 = *(const float4*)&lds[OFF_SCR + 2*SCR_SZ + S_FB + seg*64 + j*4];
      float4 f3 = *(const float4*)&lds[OFF_SCR + 3*SCR_SZ + S_FB + seg*64 + j*4];
      acc0 += w4.x*f0.x; acc0 += w4.y*f0.y; acc0 += w4.z*f0.z; acc0 += w4.w*f0.w;
      acc1 += w4.x*f1.x; acc1 += w4.y*f1.y; acc1 += w4.z*f1.z; acc1 += w4.w*f1.w;
      acc2 += w4.x*f2.x; acc2 += w4.y*f2.y; acc2 += w4.z*f2.z; acc2 += w4.w*f2.w;
      acc3 += w4.x*f3.x; acc3 += w4.y*f3.y; acc3 += w4.z*f3.z; acc3 += w4.w*f3.w;
    }
    lds[OFF_RED + seg*128 + 0*32 + o] = acc0;
    lds[OFF_RED + seg*128 + 1*32 + o] = acc1;
    lds[OFF_RED + seg*128 + 2*32 + o] = acc2;
    lds[OFF_RED + seg*128 + 3*32 + o] = acc3;
  }
  __syncthreads();

  if (t < 128) {
    int pt = t >> 5, o = t & 31;
    float yv = 0.0f;
#pragma unroll
    for (int seg = 0; seg < 8; ++seg) yv += lds[OFF_RED + seg*128 + pt*32 + o];
    lds[OFF_Y + pt*32 + o] = fmaxf(yv, 0.0f);
  }
  __syncthreads();

  {
    int pt = t >> 6, d = t & 63;
    float zv = lds[OFF_B2 + d];
#pragma unroll
    for (int o = 0; o < 32; ++o) zv += lds[OFF_Y + pt*32 + o] * lds[OFF_WL + o*64 + d];
    int gp = blockIdx.x*4 + pt;
    float cv = c[gp*64 + d];
    c[gp*64 + d] = fmaxf(zv + cv, 0.0f);
  }
}

// ---------------- triplane scatter-accumulate ----------------
__global__ void triacc_kernel(const float* __restrict__ c,
                              const float* __restrict__ xyz,
                              float* __restrict__ psum,
                              float* __restrict__ pcnt) {
  int tid = blockIdx.x * blockDim.x + threadIdx.x;
  if (tid >= NPTS*DIMM) return;
  int p = tid >> 6, d = tid & 63;
  int b = p >> 13;
  float p0 = xyz[p*3+0] / 1.101f + 0.5f;
  float p1 = xyz[p*3+1] / 1.101f + 0.5f;
  float p2 = xyz[p*3+2] / 1.101f + 0.5f;
  int i0 = min(max((int)(p0*64.0f), 0), 63);
  int i1 = min(max((int)(p1*64.0f), 0), 63);
  int i2 = min(max((int)(p2*64.0f), 0), 63);
  int cb = b*3*RESS*RESS;
  int c0 = cb + 0*RESS*RESS + i0*RESS + i1;
  int c1 = cb + 1*RESS*RESS + i0*RESS + i2;
  int c2 = cb + 2*RESS*RESS + i1*RESS + i2;
  float v = c[tid];
  atomicAdd(&psum[c0*DIMM + d], v);
  atomicAdd(&psum[c1*DIMM + d], v);
  atomicAdd(&psum[c2*DIMM + d], v);
  if (d == 0) {
    atomicAdd(&pcnt[c0], 1.0f);
    atomicAdd(&pcnt[c1], 1.0f);
    atomicAdd(&pcnt[c2], 1.0f);
  }
}

// ---------------- triplane normalize ----------------
__global__ void trinorm_kernel(const float* __restrict__ psum,
                               const float* __restrict__ pcnt,
                               float* __restrict__ out) {
  int tid = blockIdx.x * blockDim.x + threadIdx.x;
  if (tid >= PLANE_ELEMS) return;
  float cnt = pcnt[tid >> 6];
  out[tid] = psum[tid] / fmaxf(cnt, 1.0f);
}

extern "C" void kernel_launch(void* const* d_in, const int* in_sizes, int n_in,
                              void* d_out, int out_size, void* d_ws, size_t ws_size,
                              hipStream_t stream) {
  const float* xyz   = (const float*)d_in[0];
  const float* wstem = (const float*)d_in[1];
  const float* bstem = (const float*)d_in[2];
  const float* w0    = (const float*)d_in[3];
  const float* b0    = (const float*)d_in[4];
  const float* fc1   = (const float*)d_in[5];
  const float* fc2   = (const float*)d_in[6];
  const float* fc3   = (const float*)d_in[7];
  const float* wcv   = (const float*)d_in[8];
  const float* alpha = (const float*)d_in[9];
  const float* beta  = (const float*)d_in[10];
  const float* w2    = (const float*)d_in[11];
  const float* b2    = (const float*)d_in[12];

  float* out     = (float*)d_out;
  float* out_xyz = out;                       // 49152
  float* c       = out + NPTS*3;              // working c buffer
  float* out_tri = c + NPTS*DIMM;             // 1572864

  float* wsf  = (float*)d_ws;
  int*   idx  = (int*)d_ws;                   // NPTS*16 int32
  float* x    = wsf + NPTS*16;                // NPTS*32
  float* psum = x + NPTS*HH;                  // PLANE_ELEMS
  float* pcnt = psum + PLANE_ELEMS;           // PLANE_CELLS

  // knn bin arrays ALIAS psum (dead until triplane; zeroed after knn)
  int*    cellcnt   = (int*)psum;             // 1024
  int*    cellstart = (int*)psum + 1024;      // 1025 (pad to 1032)
  int*    cellcur   = (int*)psum + 2056;      // 1024
  float4* spts      = (float4*)(psum + 4096); // 16384 float4

  stem_kernel<<<(NPTS*DIMM+255)/256, 256, 0, stream>>>(xyz, wstem, bstem, out_xyz, c);
  zero_kernel<<<4, 256, 0, stream>>>((float*)cellcnt, 1024);
  knn_count_kernel<<<(NPTS+255)/256, 256, 0, stream>>>(xyz, cellcnt);
  knn_scan_kernel<<<1, 1024, 0, stream>>>(cellcnt, cellstart, cellcur);
  knn_scatter_kernel<<<(NPTS+255)/256, 256, 0, stream>>>(xyz, cellcur, spts);
  knn_query_kernel<<<1024, 64, 0, stream>>>(spts, cellstart, idx);
  for (int layer = 0; layer < NBB; ++layer) {
    xproj_kernel<<<(NPTS*HH+255)/256, 256, 0, stream>>>(c, w0, b0, x, layer);
    conv_kernel<<<NPTS/4, 256, 0, stream>>>(c, x, idx, xyz, fc1, fc2, fc3, wcv,
                                            alpha, beta, w2, b2, layer);
  }
  int nz = PLANE_ELEMS + PLANE_CELLS;
  zero_kernel<<<(nz+255)/256, 256, 0, stream>>>(psum, nz);
  triacc_kernel<<<(NPTS*DIMM+255)/256, 256, 0, stream>>>(c, xyz, psum, pcnt);
  trinorm_kernel<<<(PLANE_ELEMS+255)/256, 256, 0, stream>>>(psum, pcnt, out_tri);
}

// Round 8
// 586.440 us; speedup vs baseline: 1.2964x; 1.0082x over previous
//
#include <hip/hip_runtime.h>
#include <math.h>

#define BB 2
#define NN 8192
#define KK 16
#define DIMM 64
#define HH 32
#define NBB 5
#define RESS 64
#define NPTS (BB*NN)            // 16384
#define PLANE_ELEMS (BB*3*RESS*RESS*DIMM)   // 1572864
#define PLANE_CELLS (BB*3*RESS*RESS)        // 24576
#define GC 8                    // knn grid cells per dim
#define GCS 0.125f              // cell size
#define NCELL (GC*GC*GC)        // 512 per batch
#define CAP 2496                // staged candidate cap (box mean ~432, sd ~20)

// ---------------- zero workspace ----------------
__global__ void zero_kernel(float* __restrict__ p, int n) {
  int t = blockIdx.x * blockDim.x + threadIdx.x;
  if (t < n) p[t] = 0.0f;
}

// ---------------- stem: c = xyz @ w_stem + b_stem ; copy xyz to out ----------------
__global__ void stem_kernel(const float* __restrict__ xyz,
                            const float* __restrict__ w,
                            const float* __restrict__ bias,
                            float* __restrict__ out_xyz,
                            float* __restrict__ c) {
  int tid = blockIdx.x * blockDim.x + threadIdx.x;
  if (tid < NPTS*3) out_xyz[tid] = xyz[tid];
  if (tid < NPTS*DIMM) {
    int p = tid >> 6, d = tid & 63;
    float x = xyz[p*3+0], y = xyz[p*3+1], z = xyz[p*3+2];
    c[tid] = x*w[d] + y*w[64+d] + z*w[128+d] + bias[d];
  }
}

// ---------------- binned exact KNN ----------------
__device__ __forceinline__ unsigned ord32(float f) {
  unsigned u = __float_as_uint(f);
  return u ^ ((unsigned)((int)u >> 31) | 0x80000000u);
}
__device__ __forceinline__ int cell_of(float v) {
  return min(max((int)((v + 0.5f) * 8.0f), 0), 7);
}

__global__ void knn_count_kernel(const float* __restrict__ xyz,
                                 int* __restrict__ cellcnt) {
  int p = blockIdx.x * blockDim.x + threadIdx.x;
  if (p >= NPTS) return;
  int bq = p >> 13;
  float px = xyz[p*3], py = xyz[p*3+1], pz = xyz[p*3+2];
  int cc = (cell_of(px) << 6) | (cell_of(py) << 3) | cell_of(pz);
  atomicAdd(&cellcnt[(bq << 9) | cc], 1);
}

__global__ __launch_bounds__(1024) void knn_scan_kernel(const int* __restrict__ cnt,
                                                        int* __restrict__ cellstart,
                                                        int* __restrict__ cellcur) {
  __shared__ int s[1024];
  int t = threadIdx.x;
  int v = cnt[t];
  s[t] = v;
  __syncthreads();
  for (int off = 1; off < 1024; off <<= 1) {
    int add = (t >= off) ? s[t-off] : 0;
    __syncthreads();
    s[t] += add;
    __syncthreads();
  }
  int inc = s[t];
  cellstart[t+1] = inc;
  if (t == 0) cellstart[0] = 0;
  cellcur[t] = inc - v;      // exclusive start, used as scatter cursor
}

__global__ void knn_scatter_kernel(const float* __restrict__ xyz,
                                   int* __restrict__ cellcur,
                                   float4* __restrict__ spts) {
  int p = blockIdx.x * blockDim.x + threadIdx.x;
  if (p >= NPTS) return;
  int bq = p >> 13;
  float px = xyz[p*3], py = xyz[p*3+1], pz = xyz[p*3+2];
  int cc = (cell_of(px) << 6) | (cell_of(py) << 3) | cell_of(pz);
  int pos = atomicAdd(&cellcur[(bq << 9) | cc], 1);
  spts[pos] = make_float4(px, py, pz, __int_as_float(p & (NN-1)));
}

// Parallel branchless insert of u64 key into per-lane sorted bd[16]; ~0ull no-op.
#define INS64(key)                                                             \
  {                                                                            \
    unsigned long long _k = (key);                                             \
    _Pragma("unroll")                                                          \
    for (int jj = 15; jj >= 1; --jj) {                                         \
      unsigned long long up = bd[jj-1];                                        \
      bool shift = _k < up;                                                    \
      bool here  = _k < bd[jj];                                                \
      unsigned long long nv = shift ? up : _k;                                 \
      bd[jj] = here ? nv : bd[jj];                                             \
    }                                                                          \
    bd[0] = (_k < bd[0]) ? _k : bd[0];                                         \
  }

// Distance test + gated insert. d2 expression textually identical to R6 (passed).
#define TRYKEY(c4)                                                             \
  {                                                                            \
    float sq = (c4).x*(c4).x + (c4).y*(c4).y + (c4).z*(c4).z;                  \
    float d2 = (qs + sq) - 2.0f*(qx*(c4).x + qy*(c4).y + qz*(c4).z);           \
    unsigned du = ord32(d2);                                                   \
    bool hit = valid && du <= hi15;                                            \
    if (__any(hit)) {                                                          \
      unsigned long long key = hit ?                                           \
          (((unsigned long long)du << 32) | (unsigned)__float_as_int((c4).w))  \
          : ~0ull;                                                             \
      INS64(key);                                                              \
      hi15 = (unsigned)(bd[15] >> 32);                                         \
    }                                                                          \
  }

// Butterfly slice merge WITH DEDUP (bugfix vs R7): after the first merge all
// slices share a common base; re-merging at later rings would re-insert shared
// keys. Keys are unique per candidate, so equality-dedup is exact; duplicates
// (and sentinel pads) become ~0ull which INS64 no-ops.
#define MERGE_STEP(MASK)                                                       \
  {                                                                            \
    unsigned long long tmp[16];                                                \
    _Pragma("unroll")                                                          \
    for (int j = 0; j < 16; ++j) tmp[j] = __shfl_xor(bd[j], MASK);             \
    _Pragma("unroll")                                                          \
    for (int j = 0; j < 16; ++j) {                                             \
      unsigned long long _in = tmp[j];                                         \
      bool dup = false;                                                        \
      _Pragma("unroll")                                                        \
      for (int jj = 0; jj < 16; ++jj) dup = dup || (bd[jj] == _in);            \
      INS64(dup ? ~0ull : _in);                                                \
    }                                                                          \
    hi15 = (unsigned)(bd[15] >> 32);                                           \
  }

// knn_query v2: 1 wave/cell; LDS-staged r=1 box; lanes = 16 queries x 4 slices.
// Exact: after ring r fully scanned+merged, unscanned points are > r*cs-1e-4
// away; u64 (ord(d2),idx) keys make selection order-independent & tie-stable.
__global__ __launch_bounds__(64) void knn_query_kernel(
    const float4* __restrict__ spts, const int* __restrict__ cellstart,
    int* __restrict__ idx) {
  __shared__ __align__(16) float4 s_cand[CAP];   // 39936 B
  __shared__ int s_ofs[28];
  __shared__ int s_jlo[27];
  int wave = blockIdx.x;            // 0..1023
  int b = wave >> 9;
  int cell = wave & 511;
  int cx = cell >> 6, cy = (cell >> 3) & 7, cz = cell & 7;
  int cb = b << 9;
  int qlo = cellstart[cb + cell], qhi = cellstart[cb + cell + 1];
  int nq = qhi - qlo;
  if (nq <= 0) return;
  int lane = threadIdx.x;
  int q = lane & 15, s = lane >> 4;

  // ---- enumerate r=1 box cells, lens, exclusive prefix (wave scan) ----
  int x0 = max(cx-1,0), x1 = min(cx+1,7);
  int y0 = max(cy-1,0), y1 = min(cy+1,7);
  int z0 = max(cz-1,0), z1 = min(cz+1,7);
  int dy = y1-y0+1, dz = z1-z0+1;
  int count = (x1-x0+1)*dy*dz;      // 8..27
  int len = 0, jlo0 = 0;
  if (lane < count) {
    int xx = x0 + lane/(dy*dz);
    int rem = lane % (dy*dz);
    int yy = y0 + rem/dz, zz = z0 + rem % dz;
    int cc = cb + (xx<<6) + (yy<<3) + zz;
    jlo0 = cellstart[cc];
    len = cellstart[cc+1] - jlo0;
  }
  int pre = len;
#pragma unroll
  for (int off = 1; off < 64; off <<= 1) {
    int v = __shfl_up(pre, off);
    if (lane >= off) pre += v;
  }
  if (lane < count) { s_ofs[lane] = pre - len; s_jlo[lane] = jlo0; }
  if (lane == count-1) s_ofs[count] = pre;
  __syncthreads();
  int total = s_ofs[count];
  int tstag = min(total, CAP);

  // ---- cooperative coalesced staging (binary search item -> cell) ----
  for (int w = lane; w < tstag; w += 64) {
    int lo2 = 0, hi2 = count-1;
    while (lo2 < hi2) { int mid = (lo2+hi2+1)>>1; if (s_ofs[mid] <= w) lo2 = mid; else hi2 = mid-1; }
    s_cand[w] = spts[s_jlo[lo2] + (w - s_ofs[lo2])];
  }
  __syncthreads();

  const unsigned thru1 = ord32((GCS - 1e-4f)*(GCS - 1e-4f));
  for (int qg = 0; qg < nq; qg += 16) {
    bool valid = (qg + q) < nq;
    float4 qv = spts[qlo + qg + (valid ? q : 0)];
    float qx = qv.x, qy = qv.y, qz = qv.z;
    float qs = qx*qx + qy*qy + qz*qz;
    unsigned long long bd[16];
#pragma unroll
    for (int j = 0; j < 16; ++j) bd[j] = ~0ull;
    unsigned hi15 = 0xFFFFFFFFu;

    // LDS scan: slice s takes a contiguous quarter
    int chunk = (tstag + 3) >> 2;
    int jb = s*chunk, je = min(jb+chunk, tstag);
    for (int j = jb; j < je; ++j) {
      float4 c4 = s_cand[j];
      TRYKEY(c4);
    }
    // overflow remainder (box > CAP): scan from global, strided by slice
    if (total > CAP) {
      for (int i = 0; i < count; ++i) {
        int ofs_i = s_ofs[i], len_i = s_ofs[i+1]-ofs_i;
        int stg = min(max(CAP - ofs_i, 0), len_i);
        int jl = s_jlo[i] + stg, jh = s_jlo[i] + len_i;
        for (int j2 = jl + s; j2 < jh; j2 += 4) {
          float4 c4 = spts[j2];
          TRYKEY(c4);
        }
      }
    }
    MERGE_STEP(16);
    MERGE_STEP(32);
    bool done = !valid || (hi15 < thru1);
    // rings r>=2 (rare: corner/edge queries), from global
    for (int r = 2; r <= 8; ++r) {
      if (!__any(!done)) break;
      int xs0 = max(cx-r,0), xs1 = min(cx+r,7);
      int ys0 = max(cy-r,0), ys1 = min(cy+r,7);
      int zs0 = max(cz-r,0), zs1 = min(cz+r,7);
      int pr = r-1;
      for (int xx = xs0; xx <= xs1; ++xx)
      for (int yy = ys0; yy <= ys1; ++yy)
      for (int zz = zs0; zz <= zs1; ++zz) {
        if (xx >= cx-pr && xx <= cx+pr && yy >= cy-pr && yy <= cy+pr &&
            zz >= cz-pr && zz <= cz+pr) continue;
        int cc2 = cb + (xx<<6) + (yy<<3) + zz;
        int jl = cellstart[cc2], jh = cellstart[cc2+1];
        for (int j2 = jl + s; j2 < jh; j2 += 4) {
          float4 c4 = spts[j2];
          TRYKEY(c4);
        }
      }
      MERGE_STEP(16);
      MERGE_STEP(32);
      float thr2 = (float)r * GCS - 1e-4f;
      done = !valid || (hi15 < ord32(thr2*thr2));
    }
    if (valid && s == 0) {
      int n_self = __float_as_int(qv.w);
      int* op = idx + (((long)b << 13) + n_self) * 16;
#pragma unroll
      for (int j = 0; j < 16; ++j) op[j] = (int)(unsigned)(bd[j] & 0xffffffffu);
    }
  }
}

// ---------------- x = relu(c @ w0[l] + b0[l]) ----------------
__global__ void xproj_kernel(const float* __restrict__ c,
                             const float* __restrict__ w0,
                             const float* __restrict__ b0,
                             float* __restrict__ x, int layer) {
  int tid = blockIdx.x * blockDim.x + threadIdx.x;
  if (tid >= NPTS*HH) return;
  int p = tid >> 5, h = tid & 31;
  const float* w = w0 + layer*DIMM*HH;
  const float* cr = c + p*DIMM;
  float acc = b0[layer*HH + h];
#pragma unroll
  for (int d = 0; d < DIMM; ++d) acc += cr[d]*w[d*HH + h];
  x[tid] = fmaxf(acc, 0.0f);
}

// ---------------- fused FKAConv v3: 256 thr = 4 waves = 4 points ----------------
#define OFF_W1   0
#define OFF_W2AT 48
#define OFF_W2BT 368
#define OFF_W3AT 688
#define OFF_W3BT 1008
#define OFF_WL   1328
#define OFF_B2   3376
#define OFF_RED  3440
#define OFF_Y    4464
#define OFF_SCR  4592
#define SCR_SZ   1296
#define S_DW 0
#define S_M1 16
#define S_M2 272
#define S_MM 528
#define S_XN 784
#define S_FB 16            // overlays M1+M2 (dead after stage C)
#define LDS_TOT (OFF_SCR + 4*SCR_SZ)   // 9776 floats = 39104 B -> 4 blocks/CU

__global__ __launch_bounds__(256) void conv_kernel(
    float* __restrict__ c, const float* __restrict__ x,
    const int* __restrict__ idx, const float* __restrict__ xyz,
    const float* __restrict__ fc1, const float* __restrict__ fc2,
    const float* __restrict__ fc3, const float* __restrict__ wcv,
    const float* __restrict__ alpha, const float* __restrict__ beta,
    const float* __restrict__ w2, const float* __restrict__ b2, int layer)
{
  __shared__ __align__(16) float lds[LDS_TOT];
  int t = threadIdx.x;

  const float* fc1l = fc1 + layer*3*KK;
  const float* fc2l = fc2 + layer*2*KK*KK;
  const float* fc3l = fc3 + layer*2*KK*KK;
  const float* wcvl = wcv + layer*HH*HH*KK;
  const float* w2l  = w2  + layer*HH*DIMM;
  const float* b2l  = b2  + layer*DIMM;

  if (t < 48) lds[OFF_W1 + t] = fc1l[t];
  {
    int s = t >> 4, tt = t & 15;
    lds[OFF_W2AT + s*20 + tt] = fc2l[tt*16 + s];
    lds[OFF_W2BT + s*20 + tt] = fc2l[(16+tt)*16 + s];
    lds[OFF_W3AT + s*20 + tt] = fc3l[tt*16 + s];
    lds[OFF_W3BT + s*20 + tt] = fc3l[(16+tt)*16 + s];
  }
#pragma unroll
  for (int r = 0; r < 8; ++r) lds[OFF_WL + t + 256*r] = w2l[t + 256*r];
  if (t < 64) lds[OFF_B2 + t] = b2l[t];
  __syncthreads();

  int wv = t >> 6, lane = t & 63;
  int p = blockIdx.x*4 + wv;
  int b = p >> 13;
  float* scr = lds + OFF_SCR + wv*SCR_SZ;
  int sI = lane & 15;

  float qxx = xyz[p*3+0], qyy = xyz[p*3+1], qzz = xyz[p*3+2];
  float alv = alpha[layer], bev = beta[layer];
  int jidx = 0; float px = 0, py = 0, pz = 0, sv = 0;
  if (lane < 16) {
    jidx = idx[p*16 + lane];
    const float* nb = xyz + ((long)b*NN + jidx)*3;
    px = nb[0]-qxx; py = nb[1]-qyy; pz = nb[2]-qzz;
    float dd = sqrtf(px*px + py*py + pz*pz + 1e-12f);
    sv = 1.0f/(1.0f + expf(alv*dd - bev));
  }
  float ssum = 0.0f;
#pragma unroll
  for (int k = 0; k < 16; ++k) ssum += __shfl(sv, k);
  if (lane < 16) scr[S_DW + lane] = sv / (ssum + 1e-6f) * 16.0f;
#pragma unroll
  for (int r = 0; r < 2; ++r) {
    int tsk = lane + 64*r;
    int k = tsk >> 3, seg = tsk & 7;
    int jk = __shfl(jidx, k);
    float4 v = *(const float4*)(x + ((long)b*NN + jk)*32 + seg*4);
    *(float4*)&scr[S_XN + k*32 + seg*4] = v;
  }
#pragma unroll
  for (int r = 0; r < 4; ++r) {
    int k = (lane >> 4) + 4*r;
    float pxk = __shfl(px, k), pyk = __shfl(py, k), pzk = __shfl(pz, k);
    float v = pxk*lds[OFF_W1+sI] + pyk*lds[OFF_W1+16+sI] + pzk*lds[OFF_W1+32+sI];
    scr[S_M1 + k*16 + sI] = fmaxf(v, 0.0f);
  }
  __syncthreads();

  {
    float mpv = 0.0f;
#pragma unroll
    for (int k = 0; k < 16; ++k) mpv = fmaxf(mpv, scr[S_M1 + k*16 + sI] * scr[S_DW + k]);
    float qv = 0.0f;
#pragma unroll
    for (int tt = 0; tt < 16; ++tt) qv += __shfl(mpv, tt) * lds[OFF_W2BT + sI*20 + tt];
    float4 wa0 = *(float4*)&lds[OFF_W2AT + sI*20 + 0];
    float4 wa1 = *(float4*)&lds[OFF_W2AT + sI*20 + 4];
    float4 wa2 = *(float4*)&lds[OFF_W2AT + sI*20 + 8];
    float4 wa3 = *(float4*)&lds[OFF_W2AT + sI*20 + 12];
#pragma unroll
    for (int r = 0; r < 4; ++r) {
      int k = (lane >> 4) + 4*r;
      float4 m0 = *(float4*)&scr[S_M1 + k*16 + 0];
      float4 m1_ = *(float4*)&scr[S_M1 + k*16 + 4];
      float4 m2_ = *(float4*)&scr[S_M1 + k*16 + 8];
      float4 m3_ = *(float4*)&scr[S_M1 + k*16 + 12];
      float v = qv;
      v += m0.x*wa0.x; v += m0.y*wa0.y; v += m0.z*wa0.z; v += m0.w*wa0.w;
      v += m1_.x*wa1.x; v += m1_.y*wa1.y; v += m1_.z*wa1.z; v += m1_.w*wa1.w;
      v += m2_.x*wa2.x; v += m2_.y*wa2.y; v += m2_.z*wa2.z; v += m2_.w*wa2.w;
      v += m3_.x*wa3.x; v += m3_.y*wa3.y; v += m3_.z*wa3.z; v += m3_.w*wa3.w;
      scr[S_M2 + k*16 + sI] = fmaxf(v, 0.0f);
    }
  }
  __syncthreads();

  {
    float mpv = 0.0f;
#pragma unroll
    for (int k = 0; k < 16; ++k) mpv = fmaxf(mpv, scr[S_M2 + k*16 + sI] * scr[S_DW + k]);
    float qv = 0.0f;
#pragma unroll
    for (int tt = 0; tt < 16; ++tt) qv += __shfl(mpv, tt) * lds[OFF_W3BT + sI*20 + tt];
    float4 wa0 = *(float4*)&lds[OFF_W3AT + sI*20 + 0];
    float4 wa1 = *(float4*)&lds[OFF_W3AT + sI*20 + 4];
    float4 wa2 = *(float4*)&lds[OFF_W3AT + sI*20 + 8];
    float4 wa3 = *(float4*)&lds[OFF_W3AT + sI*20 + 12];
#pragma unroll
    for (int r = 0; r < 4; ++r) {
      int k = (lane >> 4) + 4*r;
      float4 m0 = *(float4*)&scr[S_M2 + k*16 + 0];
      float4 m1_ = *(float4*)&scr[S_M2 + k*16 + 4];
      float4 m2_ = *(float4*)&scr[S_M2 + k*16 + 8];
      float4 m3_ = *(float4*)&scr[S_M2 + k*16 + 12];
      float v = qv;
      v += m0.x*wa0.x; v += m0.y*wa0.y; v += m0.z*wa0.z; v += m0.w*wa0.w;
      v += m1_.x*wa1.x; v += m1_.y*wa1.y; v += m1_.z*wa1.z; v += m1_.w*wa1.w;
      v += m2_.x*wa2.x; v += m2_.y*wa2.y; v += m2_.z*wa2.z; v += m2_.w*wa2.w;
      v += m3_.x*wa3.x; v += m3_.y*wa3.y; v += m3_.z*wa3.z; v += m3_.w*wa3.w;
      scr[S_MM + k*16 + sI] = fmaxf(v, 0.0f) * scr[S_DW + k];
    }
  }
  __syncthreads();

  {
    int q4 = lane >> 4;
    float fr0=0,fr1=0,fr2=0,fr3=0,fr4=0,fr5=0,fr6=0,fr7=0;
#pragma unroll
    for (int k = 0; k < 16; ++k) {
      float mmv = scr[S_MM + k*16 + sI];
      float4 a  = *(float4*)&scr[S_XN + k*32 + q4*8];
      float4 bb = *(float4*)&scr[S_XN + k*32 + q4*8 + 4];
      fr0 += a.x*mmv;  fr1 += a.y*mmv;  fr2 += a.z*mmv;  fr3 += a.w*mmv;
      fr4 += bb.x*mmv; fr5 += bb.y*mmv; fr6 += bb.z*mmv; fr7 += bb.w*mmv;
    }
    scr[S_FB + (q4*8+0)*16 + sI] = fr0;
    scr[S_FB + (q4*8+1)*16 + sI] = fr1;
    scr[S_FB + (q4*8+2)*16 + sI] = fr2;
    scr[S_FB + (q4*8+3)*16 + sI] = fr3;
    scr[S_FB + (q4*8+4)*16 + sI] = fr4;
    scr[S_FB + (q4*8+5)*16 + sI] = fr5;
    scr[S_FB + (q4*8+6)*16 + sI] = fr6;
    scr[S_FB + (q4*8+7)*16 + sI] = fr7;
  }
  __syncthreads();

  {
    int o = t & 31, seg = t >> 5;
    const float4* wrow = (const float4*)(wcvl + o*512 + seg*64);
    float acc0=0, acc1=0, acc2=0, acc3=0;
#pragma unroll
    for (int j = 0; j < 16; ++j) {
      float4 w4 = wrow[j];
      float4 f0 = *(const float4*)&lds[OFF_SCR + 0*SCR_SZ + S_FB + seg*64 + j*4];
      float4 f1 = *(const float4*)&lds[OFF_SCR + 1*SCR_SZ + S_FB + seg*64 + j*4];
      float4 f2 = *(const float4*)&lds[OFF_SCR + 2*SCR_SZ + S_FB + seg*64 + j*4];
      float4 f3 = *(const float4*)&lds[OFF_SCR + 3*SCR_SZ + S_FB + seg*64 + j*4];
      acc0 += w4.x*f0.x; acc0 += w4.y*f0.y; acc0 += w4.z*f0.z; acc0 += w4.w*f0.w;
      acc1 += w4.x*f1.x; acc1 += w4.y*f1.y; acc1 += w4.z*f1.z; acc1 += w4.w*f1.w;
      acc2 += w4.x*f2.x; acc2 += w4.y*f2.y; acc2 += w4.z*f2.z; acc2 += w4.w*f2.w;
      acc3 += w4.x*f3.x; acc3 += w4.y*f3.y; acc3 += w4.z*f3.z; acc3 += w4.w*f3.w;
    }
    lds[OFF_RED + seg*128 + 0*32 + o] = acc0;
    lds[OFF_RED + seg*128 + 1*32 + o] = acc1;
    lds[OFF_RED + seg*128 + 2*32 + o] = acc2;
    lds[OFF_RED + seg*128 + 3*32 + o] = acc3;
  }
  __syncthreads();

  if (t < 128) {
    int pt = t >> 5, o = t & 31;
    float yv = 0.0f;
#pragma unroll
    for (int seg = 0; seg < 8; ++seg) yv += lds[OFF_RED + seg*128 + pt*32 + o];
    lds[OFF_Y + pt*32 + o] = fmaxf(yv, 0.0f);
  }
  __syncthreads();

  {
    int pt = t >> 6, d = t & 63;
    float zv = lds[OFF_B2 + d];
#pragma unroll
    for (int o = 0; o < 32; ++o) zv += lds[OFF_Y + pt*32 + o] * lds[OFF_WL + o*64 + d];
    int gp = blockIdx.x*4 + pt;
    float cv = c[gp*64 + d];
    c[gp*64 + d] = fmaxf(zv + cv, 0.0f);
  }
}

// ---------------- triplane scatter-accumulate ----------------
__global__ void triacc_kernel(const float* __restrict__ c,
                              const float* __restrict__ xyz,
                              float* __restrict__ psum,
                              float* __restrict__ pcnt) {
  int tid = blockIdx.x * blockDim.x + threadIdx.x;
  if (tid >= NPTS*DIMM) return;
  int p = tid >> 6, d = tid & 63;
  int b = p >> 13;
  float p0 = xyz[p*3+0] / 1.101f + 0.5f;
  float p1 = xyz[p*3+1] / 1.101f + 0.5f;
  float p2 = xyz[p*3+2] / 1.101f + 0.5f;
  int i0 = min(max((int)(p0*64.0f), 0), 63);
  int i1 = min(max((int)(p1*64.0f), 0), 63);
  int i2 = min(max((int)(p2*64.0f), 0), 63);
  int cb = b*3*RESS*RESS;
  int c0 = cb + 0*RESS*RESS + i0*RESS + i1;
  int c1 = cb + 1*RESS*RESS + i0*RESS + i2;
  int c2 = cb + 2*RESS*RESS + i1*RESS + i2;
  float v = c[tid];
  atomicAdd(&psum[c0*DIMM + d], v);
  atomicAdd(&psum[c1*DIMM + d], v);
  atomicAdd(&psum[c2*DIMM + d], v);
  if (d == 0) {
    atomicAdd(&pcnt[c0], 1.0f);
    atomicAdd(&pcnt[c1], 1.0f);
    atomicAdd(&pcnt[c2], 1.0f);
  }
}

// ---------------- triplane normalize ----------------
__global__ void trinorm_kernel(const float* __restrict__ psum,
                               const float* __restrict__ pcnt,
                               float* __restrict__ out) {
  int tid = blockIdx.x * blockDim.x + threadIdx.x;
  if (tid >= PLANE_ELEMS) return;
  float cnt = pcnt[tid >> 6];
  out[tid] = psum[tid] / fmaxf(cnt, 1.0f);
}

extern "C" void kernel_launch(void* const* d_in, const int* in_sizes, int n_in,
                              void* d_out, int out_size, void* d_ws, size_t ws_size,
                              hipStream_t stream) {
  const float* xyz   = (const float*)d_in[0];
  const float* wstem = (const float*)d_in[1];
  const float* bstem = (const float*)d_in[2];
  const float* w0    = (const float*)d_in[3];
  const float* b0    = (const float*)d_in[4];
  const float* fc1   = (const float*)d_in[5];
  const float* fc2   = (const float*)d_in[6];
  const float* fc3   = (const float*)d_in[7];
  const float* wcv   = (const float*)d_in[8];
  const float* alpha = (const float*)d_in[9];
  const float* beta  = (const float*)d_in[10];
  const float* w2    = (const float*)d_in[11];
  const float* b2    = (const float*)d_in[12];

  float* out     = (float*)d_out;
  float* out_xyz = out;                       // 49152
  float* c       = out + NPTS*3;              // working c buffer
  float* out_tri = c + NPTS*DIMM;             // 1572864

  float* wsf  = (float*)d_ws;
  int*   idx  = (int*)d_ws;                   // NPTS*16 int32
  float* x    = wsf + NPTS*16;                // NPTS*32
  float* psum = x + NPTS*HH;                  // PLANE_ELEMS
  float* pcnt = psum + PLANE_ELEMS;           // PLANE_CELLS

  // knn bin arrays ALIAS psum (dead until triplane; zeroed after knn)
  int*    cellcnt   = (int*)psum;             // 1024
  int*    cellstart = (int*)psum + 1024;      // 1025 (pad to 1032)
  int*    cellcur   = (int*)psum + 2056;      // 1024
  float4* spts      = (float4*)(psum + 4096); // 16384 float4

  stem_kernel<<<(NPTS*DIMM+255)/256, 256, 0, stream>>>(xyz, wstem, bstem, out_xyz, c);
  zero_kernel<<<4, 256, 0, stream>>>((float*)cellcnt, 1024);
  knn_count_kernel<<<(NPTS+255)/256, 256, 0, stream>>>(xyz, cellcnt);
  knn_scan_kernel<<<1, 1024, 0, stream>>>(cellcnt, cellstart, cellcur);
  knn_scatter_kernel<<<(NPTS+255)/256, 256, 0, stream>>>(xyz, cellcur, spts);
  knn_query_kernel<<<1024, 64, 0, stream>>>(spts, cellstart, idx);
  for (int layer = 0; layer < NBB; ++layer) {
    xproj_kernel<<<(NPTS*HH+255)/256, 256, 0, stream>>>(c, w0, b0, x, layer);
    conv_kernel<<<NPTS/4, 256, 0, stream>>>(c, x, idx, xyz, fc1, fc2, fc3, wcv,
                                            alpha, beta, w2, b2, layer);
  }
  int nz = PLANE_ELEMS + PLANE_CELLS;
  zero_kernel<<<(nz+255)/256, 256, 0, stream>>>(psum, nz);
  triacc_kernel<<<(NPTS*DIMM+255)/256, 256, 0, stream>>>(c, xyz, psum, pcnt);
  trinorm_kernel<<<(PLANE_ELEMS+255)/256, 256, 0, stream>>>(psum, pcnt, out_tri);
}